// Round 11
// baseline (204.125 us; speedup 1.0000x reference)
//
#include <hip/hip_runtime.h>
#include <math.h>

#define NB 8
#define NQ 256
#define NK 256
#define DIN 10
#define FDIM 64
#define HIDDEN 256
#define NH 8
#define ROWS_PER_BLK 4

#define HS2 264       // shorts per h_s / w2_s row (256 + 8 pad) -> 528 B

typedef float f32x4 __attribute__((ext_vector_type(4)));
typedef short bf16x8 __attribute__((ext_vector_type(8)));

// fast float->bf16: round-to-nearest, ties away (2 instrs)
__device__ __forceinline__ short f2bf(float f) {
    return (short)((__float_as_uint(f) + 0x8000u) >> 16);
}
// pack two floats -> two bf16 in one dword (2 adds + 1 perm)
__device__ __forceinline__ unsigned pack2(float a, float b) {
    unsigned ua = __float_as_uint(a) + 0x8000u;   // -> low half
    unsigned ub = __float_as_uint(b) + 0x8000u;   // -> high half
    return __builtin_amdgcn_perm(ub, ua, 0x07060302);
}

__device__ __forceinline__ void four4(float x, float* dst) {
    float s1 = __sinf(x), c1 = __cosf(x);
    float s2 = 2.f * s1 * c1, c2 = 1.f - 2.f * s1 * s1;
    float s4 = 2.f * s2 * c2, c4 = 1.f - 2.f * s2 * s2;
    float s8 = 2.f * s4 * c4, c8 = 1.f - 2.f * s4 * s4;
    dst[0] = s1; dst[1] = s2; dst[2] = s4; dst[3] = s8;
    dst[4] = c1; dst[5] = c2; dst[6] = c4; dst[7] = c8;
}
__device__ __forceinline__ void four2(float x, float* dst) {
    float s1 = __sinf(x), c1 = __cosf(x);
    dst[0] = s1; dst[1] = 2.f * s1 * c1;
    dst[2] = c1; dst[3] = 1.f - 2.f * s1 * s1;
}

// ---- prep: W1[feat][hidden] fp32 -> w1t[hidden][feat] bf16, scaled by
// -log2(e), feat packed in 8-blocks XOR-swizzled by (hidden&7). 32 KB.
__global__ __launch_bounds__(256, 1) void prep_w1(
    const float* __restrict__ W1, short* __restrict__ w1t)
{
    const int t = threadIdx.x;   // hidden
    const int fb = blockIdx.x;   // feat 8-block 0..7
    float v[8];
#pragma unroll
    for (int e = 0; e < 8; ++e)
        v[e] = -1.44269504f * W1[(size_t)(fb * 8 + e) * HIDDEN + t];
    uint4 pk;
    pk.x = pack2(v[0], v[1]); pk.y = pack2(v[2], v[3]);
    pk.z = pack2(v[4], v[5]); pk.w = pack2(v[6], v[7]);
    *(uint4*)&w1t[t * FDIM + ((fb ^ (t & 7)) * 8)] = pk;
}

// ---- main: block = (b, i0..i0+3), 4 waves; wave w owns pairs [64w,64w+64).
// Per row, per wave: 4 chunks of 16 pairs; each chunk does GEMM1'
// (D[h][p], A = w1t from GLOBAL (L2-hot), B = feat^T from own feat_s rows),
// silu -> private h_s region, GEMM2 (A = h pair-major, B = w2_s o-major,
// r2/r7-proven), float4 stores. ALL LDS producer=consumer same-wave ->
// ONE barrier per block (post-staging). LDS 71808 B -> 2 blocks/CU.
__global__ __launch_bounds__(256, 2) void relfeat_mfma_kernel(
    const float* __restrict__ q, const float* __restrict__ k,
    const short* __restrict__ w1t, const float* __restrict__ b1,
    const float* __restrict__ W2, const float* __restrict__ b2,
    float* __restrict__ out)
{
    __shared__ __align__(16) short feat_s[NK * FDIM];      // 32768 B
    __shared__ __align__(16) short h_s[4 * 16 * HS2];      // 33792 B
    __shared__ __align__(16) short w2_s[8 * HS2];          //  4224 B
    __shared__ __align__(16) float b1_s[HIDDEN];           //  1024 B

    const int t = threadIdx.x;
    const int wave = t >> 6;
    const int l15 = t & 15;
    const int quad = (t >> 4) & 3;
    const int b = blockIdx.x >> 6;
    const int i0 = (blockIdx.x & 63) * ROWS_PER_BLK;
    const int swr = l15 & 7;
    const int hbase = wave * 16 * HS2;   // private h_s region (shorts)

    // ---- k-row for pair j = t (block-invariant) ----
    const float* kp = k + ((size_t)b * NK + t) * DIN;
    const float k0 = kp[0], k3 = kp[3], k4 = kp[4], k5 = kp[5], k6 = kp[6],
                k7 = kp[7], k8 = kp[8];

    // ---- staging: w2 (o-major, -ln2 scaled), b1 (-log2e scaled) ----
#pragma unroll
    for (int o = 0; o < NH; ++o)
        w2_s[o * HS2 + t] = f2bf(-0.69314718f * W2[t * NH + o]);
    b1_s[t] = -1.44269504f * b1[t];
    const float b2v = (l15 < NH) ? b2[l15] : 0.f;

    __syncthreads();  // the ONLY barrier

    // ================= row loop =================
#pragma unroll 1
    for (int row = 0; row < ROWS_PER_BLK; ++row) {
        const int i = i0 + row;

        // ---- features for pair j = t (r5-proven math, r7-proven swizzle);
        //      reader = own wave -> no barrier ----
        {
            const float* qp = q + ((size_t)b * NQ + i) * DIN;
            const float q0 = qp[0], q3 = qp[3], q4 = qp[4], q5 = qp[5],
                        q6 = qp[6], q7 = qp[7], q8 = qp[8];

            const float dpx = k3 - q3, dpy = k4 - q4;
            const float dvx = k5 - q5, dvy = k6 - q6;
            const float dist = sqrtf(dpx * dpx + dpy * dpy + 1e-6f);
            const float inv_dist = 1.0f / (dist + 0.1f);
            const float inv_d2 = 1.0f / (dist + 1e-6f);
            const float bear_x = dpx * inv_d2, bear_y = dpy * inv_d2;
            const float ata = bear_x * q7 + bear_y * q8;
            const float aspect = bear_x * k7 + bear_y * k8;
            const float dot_dp_dv = dpx * dvx + dpy * dvy;
            const float speed_sq = dvx * dvx + dvy * dvy;
            const float ttca = tanhf(fmaxf(0.f, -dot_dp_dv / (speed_sq + 1e-6f)));
            const float same_team = (q0 == k0) ? 1.f : 0.f;
            const float q_speed = sqrtf(q5 * q5 + q6 * q6);
            const float k_speed = sqrtf(k5 * k5 + k6 * k6);
            const float delta_speed = k_speed - q_speed;

            float feat[FDIM];
            four4(dist,        feat + 0);
            four4(inv_dist,    feat + 8);
            four4(ata,         feat + 16);
            four4(aspect,      feat + 24);
            four2(dpx,         feat + 32);
            four2(dpy,         feat + 36);
            four2(dvx,         feat + 40);
            four2(dvy,         feat + 44);
            four2(ttca,        feat + 48);
            four2(dist,        feat + 52);
            four2(same_team,   feat + 56);
            four2(delta_speed, feat + 60);

            const int sw = t & 7;
#pragma unroll
            for (int c8 = 0; c8 < 8; ++c8) {
                uint4 v;
                v.x = pack2(feat[c8 * 8 + 0], feat[c8 * 8 + 1]);
                v.y = pack2(feat[c8 * 8 + 2], feat[c8 * 8 + 3]);
                v.z = pack2(feat[c8 * 8 + 4], feat[c8 * 8 + 5]);
                v.w = pack2(feat[c8 * 8 + 6], feat[c8 * 8 + 7]);
                *(uint4*)&feat_s[t * FDIM + ((c8 ^ sw) * 8)] = v;
            }
        }

        // ---- 4 chunks of 16 pairs, barrier-free ----
#pragma unroll 1
        for (int c = 0; c < 4; ++c) {
            const int p0 = wave * 64 + c * 16;

            // GEMM1': D[hidden][pair]; A = w1t (global, L2), B = feat^T (LDS)
            f32x4 acc[16];
#pragma unroll
            for (int mt = 0; mt < 16; ++mt) acc[mt] = (f32x4){0.f, 0.f, 0.f, 0.f};

            const bf16x8 fb0 = *(const bf16x8*)
                &feat_s[(p0 + l15) * FDIM + ((quad ^ swr) * 8)];
            const bf16x8 fb1 = *(const bf16x8*)
                &feat_s[(p0 + l15) * FDIM + (((4 + quad) ^ swr) * 8)];
#pragma unroll
            for (int mt = 0; mt < 16; ++mt) {
                const bf16x8 a0 = *(const bf16x8*)
                    &w1t[(mt * 16 + l15) * FDIM + ((quad ^ swr) * 8)];
                acc[mt] = __builtin_amdgcn_mfma_f32_16x16x32_bf16(a0, fb0, acc[mt], 0, 0, 0);
            }
#pragma unroll
            for (int mt = 0; mt < 16; ++mt) {
                const bf16x8 a1 = *(const bf16x8*)
                    &w1t[(mt * 16 + l15) * FDIM + (((4 + quad) ^ swr) * 8)];
                acc[mt] = __builtin_amdgcn_mfma_f32_16x16x32_bf16(a1, fb1, acc[mt], 0, 0, 0);
            }

            // bias + silu (scale-folded) -> private h_s (same-wave)
#pragma unroll
            for (int mt = 0; mt < 16; ++mt) {
                const float4 bv = *(const float4*)&b1_s[mt * 16 + quad * 4];
                const float a0 = acc[mt][0] + bv.x;
                const float a1 = acc[mt][1] + bv.y;
                const float a2 = acc[mt][2] + bv.z;
                const float a3 = acc[mt][3] + bv.w;
                const float s0 = a0 * __builtin_amdgcn_rcpf(1.f + __builtin_amdgcn_exp2f(a0));
                const float s1 = a1 * __builtin_amdgcn_rcpf(1.f + __builtin_amdgcn_exp2f(a1));
                const float s2 = a2 * __builtin_amdgcn_rcpf(1.f + __builtin_amdgcn_exp2f(a2));
                const float s3 = a3 * __builtin_amdgcn_rcpf(1.f + __builtin_amdgcn_exp2f(a3));
                uint2 pk;
                pk.x = pack2(s0, s1);
                pk.y = pack2(s2, s3);
                *(uint2*)&h_s[hbase + l15 * HS2 + mt * 16 + quad * 4] = pk;
            }

            // GEMM2 (r2/r7-proven orientation): A = h (pair-major), B = w2_s
            f32x4 acc2 = (f32x4){b2v, b2v, b2v, b2v};
#pragma unroll
            for (int k2 = 0; k2 < 8; ++k2) {
                const bf16x8 ha = *(const bf16x8*)
                    &h_s[hbase + l15 * HS2 + k2 * 32 + quad * 8];
                const bf16x8 wb = *(const bf16x8*)
                    &w2_s[(l15 & 7) * HS2 + k2 * 32 + quad * 8];
                acc2 = __builtin_amdgcn_mfma_f32_16x16x32_bf16(ha, wb, acc2, 0, 0, 0);
            }
            // D2[pair-local = quad*4+r][o = l15]; store out[b][o][i][p0+quad*4..+3]
            if (l15 < NH) {
                float* op = out + (((size_t)b * NH + l15) * NQ + i) * NK
                            + p0 + quad * 4;
                *(float4*)op = make_float4(acc2[0], acc2[1], acc2[2], acc2[3]);
            }
        }
    }
}

extern "C" void kernel_launch(void* const* d_in, const int* in_sizes, int n_in,
                              void* d_out, int out_size, void* d_ws, size_t ws_size,
                              hipStream_t stream) {
    const float* q  = (const float*)d_in[0];
    const float* k  = (const float*)d_in[1];
    const float* W1 = (const float*)d_in[2];
    const float* b1 = (const float*)d_in[3];
    const float* W2 = (const float*)d_in[4];
    const float* b2 = (const float*)d_in[5];
    float* out = (float*)d_out;
    short* w1t = (short*)d_ws;   // 32 KB scratch

    prep_w1<<<dim3(8), dim3(256), 0, stream>>>(W1, w1t);
    dim3 grid(NB * NQ / ROWS_PER_BLK);  // 512 blocks = 2/CU, one dispatch round
    dim3 block(NK);                     // 256 threads = 4 waves
    relfeat_mfma_kernel<<<grid, block, 0, stream>>>(q, k, w1t, b1, W2, b2, out);
}

// Round 12
// 115.368 us; speedup vs baseline: 1.7693x; 1.7693x over previous
//
#include <hip/hip_runtime.h>
#include <math.h>

#define NB 8
#define NQ 256
#define NK 256
#define DIN 10
#define FDIM 64
#define HIDDEN 256
#define NH 8
#define ROWS_PER_BLK 4

#define FSTRIDE 64    // shorts per feat row; XOR-swizzled 8-short col-blocks
#define HSTRIDE 264   // shorts per h row (256 + 8 pad) -> 528 B

typedef float f32x4 __attribute__((ext_vector_type(4)));
typedef short bf16x8 __attribute__((ext_vector_type(8)));

// fast float->bf16: round-to-nearest, ties away (2 instrs)
__device__ __forceinline__ short f2bf(float f) {
    return (short)((__float_as_uint(f) + 0x8000u) >> 16);
}
// pack two floats -> two bf16 in one dword (2 adds + 1 perm)
__device__ __forceinline__ unsigned pack2(float a, float b) {
    unsigned ua = __float_as_uint(a) + 0x8000u;   // -> low half
    unsigned ub = __float_as_uint(b) + 0x8000u;   // -> high half
    return __builtin_amdgcn_perm(ub, ua, 0x07060302);
}

__device__ __forceinline__ void four4(float x, float* dst) {
    float s1 = __sinf(x), c1 = __cosf(x);
    float s2 = 2.f * s1 * c1, c2 = 1.f - 2.f * s1 * s1;
    float s4 = 2.f * s2 * c2, c4 = 1.f - 2.f * s2 * s2;
    float s8 = 2.f * s4 * c4, c8 = 1.f - 2.f * s4 * s4;
    dst[0] = s1; dst[1] = s2; dst[2] = s4; dst[3] = s8;
    dst[4] = c1; dst[5] = c2; dst[6] = c4; dst[7] = c8;
}
__device__ __forceinline__ void four2(float x, float* dst) {
    float s1 = __sinf(x), c1 = __cosf(x);
    dst[0] = s1; dst[1] = 2.f * s1 * c1;
    dst[2] = c1; dst[3] = 1.f - 2.f * s1 * s1;
}

// Block = (b, i0..i0+3), 4 waves; grid = 512 = 2 blocks/CU, one dispatch round.
// Per row: 8 half-chunks of 32 pairs, h_s PING-PONG (2 x 32-row buffers),
// ONE barrier per half-chunk. GEMM1' (r10-proven transposed map) + silu by
// all waves; GEMM2(c) by wave-pair (wave>>1)==(c&1), overlapping the other
// pair's GEMM1'(c+1). W1 frags AND W2 frags in registers (w2 values per
// r3/r7: lanes 8..15 duplicate cols 0..7, outputs unused).
// Scale folds (r10-proven): W1,b1 x -log2e; W2 x -ln2.
// LDS 66560 B -> 2 blocks/CU.
__global__ __launch_bounds__(256, 2) void relfeat_mfma_kernel(
    const float* __restrict__ q, const float* __restrict__ k,
    const float* __restrict__ W1, const float* __restrict__ b1,
    const float* __restrict__ W2, const float* __restrict__ b2,
    float* __restrict__ out)
{
    __shared__ __align__(16) short feat_s[NK * FSTRIDE];     // 32768 B
    __shared__ __align__(16) short h_s[2 * 32 * HSTRIDE];    // 33792 B

    const int t = threadIdx.x;
    const int wave = t >> 6;
    const int l15 = t & 15;
    const int quad = (t >> 4) & 3;
    const int b = blockIdx.x >> 6;
    const int i0 = (blockIdx.x & 63) * ROWS_PER_BLK;
    const int swr = l15 & 7;

    // ---- k-row for pair j = t (block-invariant) ----
    const float* kp = k + ((size_t)b * NK + t) * DIN;
    const float k0 = kp[0], k3 = kp[3], k4 = kp[4], k5 = kp[5], k6 = kp[6],
                k7 = kp[7], k8 = kp[8];

    // ---- W2 B-fragments in regs, -ln2 scaled (r3 values, r7 dup-lanes) ----
    bf16x8 w2f[8];
#pragma unroll
    for (int k2 = 0; k2 < 8; ++k2) {
        bf16x8 v;
#pragma unroll
        for (int e = 0; e < 8; ++e)
            v[e] = f2bf(-0.69314718f *
                        W2[(size_t)(k2 * 32 + quad * 8 + e) * NH + (l15 & 7)]);
        w2f[k2] = v;
    }
    const float b2v = (l15 < NH) ? b2[l15] : 0.f;

    // ---- W1 fragments (A operand), -log2e scaled (r10-proven) ----
    const int n0 = wave * 64;
    bf16x8 w1f[4][2];
#pragma unroll
    for (int nt = 0; nt < 4; ++nt)
#pragma unroll
        for (int ks = 0; ks < 2; ++ks) {
            const float* wp = W1 + (size_t)(ks * 32 + quad * 8) * HIDDEN
                              + (n0 + nt * 16 + l15);
            bf16x8 v;
#pragma unroll
            for (int e = 0; e < 8; ++e)
                v[e] = f2bf(-1.44269504f * wp[(size_t)e * HIDDEN]);
            w1f[nt][ks] = v;
        }
    float4 b1q[4];
#pragma unroll
    for (int nt = 0; nt < 4; ++nt) {
        float4 bb = *(const float4*)&b1[n0 + nt * 16 + quad * 4];
        b1q[nt] = make_float4(-1.44269504f * bb.x, -1.44269504f * bb.y,
                              -1.44269504f * bb.z, -1.44269504f * bb.w);
    }

    // ================= row loop =================
#pragma unroll 1
    for (int row = 0; row < ROWS_PER_BLK; ++row) {
        const int i = i0 + row;

        // ---- features for pair j = t (r5-proven math, r7-proven swizzle) ----
        {
            const float* qp = q + ((size_t)b * NQ + i) * DIN;
            const float q0 = qp[0], q3 = qp[3], q4 = qp[4], q5 = qp[5],
                        q6 = qp[6], q7 = qp[7], q8 = qp[8];

            const float dpx = k3 - q3, dpy = k4 - q4;
            const float dvx = k5 - q5, dvy = k6 - q6;
            const float dist = sqrtf(dpx * dpx + dpy * dpy + 1e-6f);
            const float inv_dist = 1.0f / (dist + 0.1f);
            const float inv_d2 = 1.0f / (dist + 1e-6f);
            const float bear_x = dpx * inv_d2, bear_y = dpy * inv_d2;
            const float ata = bear_x * q7 + bear_y * q8;
            const float aspect = bear_x * k7 + bear_y * k8;
            const float dot_dp_dv = dpx * dvx + dpy * dvy;
            const float speed_sq = dvx * dvx + dvy * dvy;
            const float ttca = tanhf(fmaxf(0.f, -dot_dp_dv / (speed_sq + 1e-6f)));
            const float same_team = (q0 == k0) ? 1.f : 0.f;
            const float q_speed = sqrtf(q5 * q5 + q6 * q6);
            const float k_speed = sqrtf(k5 * k5 + k6 * k6);
            const float delta_speed = k_speed - q_speed;

            float feat[FDIM];
            four4(dist,        feat + 0);
            four4(inv_dist,    feat + 8);
            four4(ata,         feat + 16);
            four4(aspect,      feat + 24);
            four2(dpx,         feat + 32);
            four2(dpy,         feat + 36);
            four2(dvx,         feat + 40);
            four2(dvy,         feat + 44);
            four2(ttca,        feat + 48);
            four2(dist,        feat + 52);
            four2(same_team,   feat + 56);
            four2(delta_speed, feat + 60);

            const int sw = t & 7;
#pragma unroll
            for (int c8 = 0; c8 < 8; ++c8) {
                uint4 v;
                v.x = pack2(feat[c8 * 8 + 0], feat[c8 * 8 + 1]);
                v.y = pack2(feat[c8 * 8 + 2], feat[c8 * 8 + 3]);
                v.z = pack2(feat[c8 * 8 + 4], feat[c8 * 8 + 5]);
                v.w = pack2(feat[c8 * 8 + 6], feat[c8 * 8 + 7]);
                *(uint4*)&feat_s[t * FSTRIDE + ((c8 ^ sw) * 8)] = v;
            }
        }
        __syncthreads();  // feat_s(row) ready (prev row fully drained here)

        // ---- 8 half-chunks of 32 pairs, ping-pong h buffers ----
#pragma unroll 1
        for (int hc = 0; hc < 8; ++hc) {
            const int p0 = hc * 32;
            short* hb = &h_s[(hc & 1) * 32 * HSTRIDE];

            // GEMM1': D[hidden][pair] over 32 pairs x wave's 64 hidden
            f32x4 acc[4][2];
#pragma unroll
            for (int nt = 0; nt < 4; ++nt)
#pragma unroll
                for (int mt = 0; mt < 2; ++mt)
                    acc[nt][mt] = (f32x4){b1q[nt].x, b1q[nt].y, b1q[nt].z, b1q[nt].w};
#pragma unroll
            for (int ks = 0; ks < 2; ++ks)
#pragma unroll
                for (int mt = 0; mt < 2; ++mt) {
                    const int r2 = p0 + mt * 16 + l15;
                    const bf16x8 fb = *(const bf16x8*)
                        &feat_s[r2 * FSTRIDE + (((ks * 4 + quad) ^ swr) * 8)];
#pragma unroll
                    for (int nt = 0; nt < 4; ++nt)
                        acc[nt][mt] = __builtin_amdgcn_mfma_f32_16x16x32_bf16(
                            w1f[nt][ks], fb, acc[nt][mt], 0, 0, 0);
                }

            // silu (scale-folded) -> pack -> ds_write_b64 into ping buffer
#pragma unroll
            for (int nt = 0; nt < 4; ++nt)
#pragma unroll
                for (int mt = 0; mt < 2; ++mt) {
                    const int pair = mt * 16 + l15;
                    const int hbase = n0 + nt * 16 + quad * 4;
                    float s[4];
#pragma unroll
                    for (int r = 0; r < 4; ++r) {
                        const float a = acc[nt][mt][r];     // = -log2e * preact
                        const float e = __builtin_amdgcn_exp2f(a);
                        s[r] = a * __builtin_amdgcn_rcpf(1.f + e);
                    }
                    uint2 pk;
                    pk.x = pack2(s[0], s[1]);
                    pk.y = pack2(s[2], s[3]);
                    *(uint2*)&hb[pair * HSTRIDE + hbase] = pk;
                }
            __syncthreads();  // h(hc) ready; GEMM2(hc-1) provably complete

            // GEMM2(hc): wave-pair (wave>>1)==(hc&1); 2 x 16-pair M-tiles
            if ((wave >> 1) == (hc & 1)) {
                const int pw = (wave & 1) * 16;
                f32x4 acc2 = (f32x4){b2v, b2v, b2v, b2v};
#pragma unroll
                for (int k2 = 0; k2 < 8; ++k2) {
                    const bf16x8 ha = *(const bf16x8*)
                        &hb[(pw + l15) * HSTRIDE + k2 * 32 + quad * 8];
                    acc2 = __builtin_amdgcn_mfma_f32_16x16x32_bf16(
                        ha, w2f[k2], acc2, 0, 0, 0);
                }
                if (l15 < NH) {
                    float* op = out + (((size_t)b * NH + l15) * NQ + i) * NK
                                + (p0 + pw + quad * 4);
                    *(float4*)op = make_float4(acc2[0], acc2[1], acc2[2], acc2[3]);
                }
            }
            // no second barrier: ping-pong means silu(hc+1) writes the OTHER
            // buffer; silu(hc+2) (same buffer) is after barrier(hc+1), by
            // which time this GEMM2 has completed.
        }
    }
}

extern "C" void kernel_launch(void* const* d_in, const int* in_sizes, int n_in,
                              void* d_out, int out_size, void* d_ws, size_t ws_size,
                              hipStream_t stream) {
    const float* q  = (const float*)d_in[0];
    const float* k  = (const float*)d_in[1];
    const float* W1 = (const float*)d_in[2];
    const float* b1 = (const float*)d_in[3];
    const float* W2 = (const float*)d_in[4];
    const float* b2 = (const float*)d_in[5];
    float* out = (float*)d_out;

    dim3 grid(NB * NQ / ROWS_PER_BLK);  // 512 blocks = 2/CU, one dispatch round
    dim3 block(NK);                     // 256 threads = 4 waves
    relfeat_mfma_kernel<<<grid, block, 0, stream>>>(q, k, W1, b1, W2, b2, out);
}